// Round 4
// baseline (2414.754 us; speedup 1.0000x reference)
//
#include <hip/hip_runtime.h>
#include <cmath>

#define S_CNT 50
#define T_CNT 2048
#define I_DIM 64
#define H_DIM 256
#define NTHR  1024

__device__ __forceinline__ float fast_tanh(float x) {
    float e = __expf(2.0f * x);
    return 1.0f - __fdividef(2.0f, e + 1.0f);
}

__device__ __forceinline__ float4 f4fma(const float4 a, const float4 b, const float4 c) {
    return make_float4(fmaf(a.x, b.x, c.x), fmaf(a.y, b.y, c.y),
                       fmaf(a.z, b.z, c.z), fmaf(a.w, b.w, c.w));
}

__device__ __forceinline__ float fma4(const float4 w, const float4 h, float a) {
    a = fmaf(w.x, h.x, a);
    a = fmaf(w.y, h.y, a);
    a = fmaf(w.z, h.z, a);
    a = fmaf(w.w, h.w, a);
    return a;
}

// U[s][t][j] = b_ih[s][j] + b_hh[s][j] + W_ih[s][j]·x[s][t]
__launch_bounds__(256, 4)
__global__ void precompute_u_kernel(const float* __restrict__ input_data,
                                    const float* __restrict__ W_ih,
                                    const float* __restrict__ b_ih,
                                    const float* __restrict__ b_hh,
                                    float* __restrict__ U)
{
    const int s  = blockIdx.x;
    const int tb = blockIdx.y;   // 16 t-slices of 128 steps
    const int j  = threadIdx.x;

    float4 w[16];
    const float4* wrow =
        reinterpret_cast<const float4*>(W_ih + ((size_t)s * H_DIM + j) * I_DIM);
#pragma unroll
    for (int k = 0; k < 16; ++k) w[k] = wrow[k];
    const float bsum = b_ih[s * H_DIM + j] + b_hh[s * H_DIM + j];

    __shared__ float xs[32][I_DIM];
    const float* inb = input_data + (size_t)s * T_CNT * 65;
    float* Ub = U + (size_t)s * T_CNT * H_DIM;

    for (int c = 0; c < 4; ++c) {
        const int t0 = tb * 128 + c * 32;
        __syncthreads();
        for (int idx = j; idx < 32 * I_DIM; idx += 256) {
            const int row = idx >> 6, col = idx & 63;
            xs[row][col] = inb[(size_t)(t0 + row) * 65 + 1 + col];
        }
        __syncthreads();
        for (int tt = 0; tt < 32; ++tt) {
            const float4* xv = reinterpret_cast<const float4*>(&xs[tt][0]);
            float a0 = bsum, a1 = 0.f, a2 = 0.f, a3 = 0.f;
#pragma unroll
            for (int k = 0; k < 16; k += 4) {
                a0 = fma4(w[k],     xv[k],     a0);
                a1 = fma4(w[k + 1], xv[k + 1], a1);
                a2 = fma4(w[k + 2], xv[k + 2], a2);
                a3 = fma4(w[k + 3], xv[k + 3], a3);
            }
            Ub[(size_t)(t0 + tt) * H_DIM + j] = (a0 + a1) + (a2 + a3);
        }
    }
}

// Main recurrence. tid = g*8 + p: thread owns rows {2g, 2g+1} and float4
// col-chunks f = m*8 + p (m=0..7) of W_hh. h chunk reused for both rows.
// Dot reduce: butterfly over p (strides 1,2,4). Sigma: per-wave partial via
// strides 8,16,32 (group-uniform values, no masking), stored to P[s][t][wv];
// a post-kernel finalizes sigma/log-lik off the critical path.
__global__ __launch_bounds__(NTHR)
__attribute__((amdgpu_waves_per_eu(4, 4)))
void rnn_main2(const float* __restrict__ hidden,
               const float* __restrict__ W_hh,
               const float* __restrict__ W_lin,
               const float* __restrict__ U,
               float* __restrict__ P)
{
    const int s    = blockIdx.x;
    const int tid  = threadIdx.x;
    const int g    = tid >> 3;    // 0..127 row pair
    const int p    = tid & 7;     // col slice
    const int lane = tid & 63;
    const int wv   = tid >> 6;    // 0..15

    __shared__ float hbuf[2][H_DIM];

    if (tid < H_DIM) hbuf[1][tid] = hidden[s * H_DIM + tid];

    // weights: rows 2g (A) and 2g+1 (B), chunks m*8+p
    const float4* wrA =
        reinterpret_cast<const float4*>(W_hh + ((size_t)s * H_DIM + 2 * g) * H_DIM);
    const float4* wrB = wrA + (H_DIM / 4);
    float4 wA[8], wB[8];
#pragma unroll
    for (int m = 0; m < 8; ++m) {
        wA[m] = wrA[m * 8 + p];
        wB[m] = wrB[m * 8 + p];
    }

    const float2 wl = *reinterpret_cast<const float2*>(W_lin + s * H_DIM + 2 * g);

    const float2* Up =
        reinterpret_cast<const float2*>(U + (size_t)s * T_CNT * H_DIM) + g;
    float2 ucur = Up[0];

    float* Pb = P + (size_t)s * T_CNT * 16;

    __syncthreads();

    for (int t = 0; t < T_CNT; ++t) {
        // prefetch next step's u (latency hidden under matvec)
        const int tn = (t + 1 < T_CNT) ? (t + 1) : t;
        const float2 unext = Up[(size_t)tn * (H_DIM / 2)];

        const float4* hv =
            reinterpret_cast<const float4*>(&hbuf[(t + 1) & 1][0]) + p;

        float4 accA = make_float4(0.f, 0.f, 0.f, 0.f);
        float4 accB = make_float4(0.f, 0.f, 0.f, 0.f);
#pragma unroll
        for (int m = 0; m < 8; ++m) {
            const float4 h4 = hv[m * 8];
            accA = f4fma(wA[m], h4, accA);
            accB = f4fma(wB[m], h4, accB);
        }
        float dA = (accA.x + accA.y) + (accA.z + accA.w);
        float dB = (accB.x + accB.y) + (accB.z + accB.w);

        // reduce across the 8-lane col split
        dA += __shfl_xor(dA, 1); dB += __shfl_xor(dB, 1);
        dA += __shfl_xor(dA, 2); dB += __shfl_xor(dB, 2);
        dA += __shfl_xor(dA, 4); dB += __shfl_xor(dB, 4);

        const float hA = fast_tanh(dA + ucur.x);
        const float hB = fast_tanh(dB + ucur.y);

        if (p == 0)
            *reinterpret_cast<float2*>(&hbuf[t & 1][2 * g]) = make_float2(hA, hB);

        // per-wave sigma partial: values are uniform within each 8-group,
        // so strides 8,16,32 sum exactly the 8 groups of this wave.
        float sv = fmaf(hA, wl.x, hB * wl.y);
        sv += __shfl_xor(sv, 8);
        sv += __shfl_xor(sv, 16);
        sv += __shfl_xor(sv, 32);
        if (lane == 0) Pb[(size_t)t * 16 + wv] = sv;

        ucur = unext;
        __syncthreads();
    }
}

// finalize: sigma[s][t] = |sum_w P[s][t][w] + b_lin[s]|, log-lik reduction
__launch_bounds__(256, 4)
__global__ void finalize_kernel(const float* __restrict__ input_data,
                                const float* __restrict__ fe,
                                const float* __restrict__ b_lin,
                                const float* __restrict__ P,
                                float* __restrict__ out)
{
    const int s   = blockIdx.x;
    const int tid = threadIdx.x;
    const float blin = b_lin[s];
    const float* Pb  = P + (size_t)s * T_CNT * 16;
    const float* inb = input_data + (size_t)s * T_CNT * 65;
    const float* feb = fe + (size_t)s * T_CNT;
    float* sig_out   = out + 1 + (size_t)s * T_CNT;

    float ll = 0.f;
    for (int t = tid; t < T_CNT; t += 256) {
        const float4* pp = reinterpret_cast<const float4*>(Pb + (size_t)t * 16);
        const float4 q0 = pp[0], q1 = pp[1], q2 = pp[2], q3 = pp[3];
        float sg = (((q0.x + q0.y) + (q0.z + q0.w)) +
                    ((q1.x + q1.y) + (q1.z + q1.w))) +
                   (((q2.x + q2.y) + (q2.z + q2.w)) +
                    ((q3.x + q3.y) + (q3.z + q3.w))) + blin;
        const float sigma = fabsf(sg);
        sig_out[t] = sigma;
        const float diff = inb[(size_t)t * 65] - feb[t];
        ll -= (diff * diff) / (2.f * sigma * sigma);
    }
#pragma unroll
    for (int m = 1; m <= 32; m <<= 1) ll += __shfl_xor(ll, m);
    __shared__ float wred[4];
    if ((tid & 63) == 0) wred[tid >> 6] = ll;
    __syncthreads();
    if (tid == 0) atomicAdd(out, (wred[0] + wred[1]) + (wred[2] + wred[3]));
}

// ---------------- fallback (no workspace): round-3 style, self-contained ----
__launch_bounds__(NTHR, 4)
__global__ void rnn_fallback_kernel(const float* __restrict__ input_data,
                                    const float* __restrict__ hidden,
                                    const float* __restrict__ fe,
                                    const float* __restrict__ W_ih,
                                    const float* __restrict__ W_hh,
                                    const float* __restrict__ b_ih,
                                    const float* __restrict__ b_hh,
                                    const float* __restrict__ W_lin,
                                    const float* __restrict__ b_lin,
                                    float* __restrict__ out)
{
    const int s    = blockIdx.x;
    const int tid  = threadIdx.x;
    const int j    = tid >> 2;
    const int q    = tid & 3;
    const int lane = tid & 63;
    const int wv   = tid >> 6;

    __shared__ float hbuf[2][H_DIM];
    __shared__ float zbuf[T_CNT];
    __shared__ float febuf[T_CNT];
    __shared__ float wlin_lds[H_DIM];
    __shared__ float wsum[2][16];
    __shared__ float xbuf[64][I_DIM];

    const float* in_base = input_data + (size_t)s * T_CNT * 65;
    const float* fe_base = fe + (size_t)s * T_CNT;

    for (int t = tid; t < T_CNT; t += NTHR) {
        zbuf[t]  = in_base[(size_t)t * 65];
        febuf[t] = fe_base[t];
    }
    if (tid < H_DIM) {
        hbuf[1][tid]  = hidden[s * H_DIM + tid];
        wlin_lds[tid] = W_lin[s * H_DIM + tid];
    }

    float4 w[16];
    {
        const float4* wrow =
            reinterpret_cast<const float4*>(W_hh + ((size_t)s * H_DIM + j) * H_DIM);
#pragma unroll
        for (int m = 0; m < 16; ++m) w[m] = wrow[4 * m + q];
    }
    float4 wx[4];
    {
        const float4* wxrow =
            reinterpret_cast<const float4*>(W_ih + ((size_t)s * H_DIM + j) * I_DIM);
#pragma unroll
        for (int m = 0; m < 4; ++m) wx[m] = wxrow[4 * m + q];
    }
    const float badd = b_ih[s * H_DIM + j] + b_hh[s * H_DIM + j];
    const float blin = b_lin[s];
    float* sig_out = out + 1 + (size_t)s * T_CNT;

    float ll = 0.f, sv_prev = 0.f;
    __syncthreads();

    for (int c = 0; c < T_CNT / 64; ++c) {
        for (int idx = tid; idx < 64 * I_DIM; idx += NTHR) {
            const int row = idx >> 6, col = idx & 63;
            xbuf[row][col] = in_base[(size_t)(c * 64 + row) * 65 + 1 + col];
        }
        __syncthreads();
        for (int tt = 0; tt < 64; ++tt) {
            const int t  = c * 64 + tt;
            const int rp = (t + 1) & 1;
            {
                float sv = sv_prev;
                sv += __shfl_xor(sv, 4);
                sv += __shfl_xor(sv, 8);
                sv += __shfl_xor(sv, 16);
                sv += __shfl_xor(sv, 32);
                if (lane == 0) wsum[(t - 1) & 1][wv] = sv;
            }
            if (tid == 0 && t >= 2) {
                const int tm = t - 2;
                const float* wp = wsum[tm & 1];
                float sg = (((wp[0] + wp[1]) + (wp[2] + wp[3])) +
                            ((wp[4] + wp[5]) + (wp[6] + wp[7]))) +
                           (((wp[8] + wp[9]) + (wp[10] + wp[11])) +
                            ((wp[12] + wp[13]) + (wp[14] + wp[15]))) + blin;
                const float sigma = fabsf(sg);
                sig_out[tm] = sigma;
                const float diff = zbuf[tm] - febuf[tm];
                ll -= (diff * diff) / (2.f * sigma * sigma);
            }
            const float4* hv = reinterpret_cast<const float4*>(&hbuf[rp][0]);
            float a0 = 0.f, a1 = 0.f, a2 = 0.f, a3 = 0.f;
#pragma unroll
            for (int m = 0; m < 16; m += 4) {
                a0 = fma4(w[m],     hv[4 * (m + 0) + q], a0);
                a1 = fma4(w[m + 1], hv[4 * (m + 1) + q], a1);
                a2 = fma4(w[m + 2], hv[4 * (m + 2) + q], a2);
                a3 = fma4(w[m + 3], hv[4 * (m + 3) + q], a3);
            }
            const float4* xv = reinterpret_cast<const float4*>(&xbuf[tt][0]);
#pragma unroll
            for (int m = 0; m < 4; ++m) a0 = fma4(wx[m], xv[4 * m + q], a0);

            float dot = (a0 + a1) + (a2 + a3);
            dot += __shfl_xor(dot, 1);
            dot += __shfl_xor(dot, 2);
            const float h = fast_tanh(dot + badd);
            if (q == 0) hbuf[t & 1][j] = h;
            sv_prev = h * wlin_lds[j];
            __syncthreads();
        }
        __syncthreads();
    }
    {
        float sv = sv_prev;
        sv += __shfl_xor(sv, 4);
        sv += __shfl_xor(sv, 8);
        sv += __shfl_xor(sv, 16);
        sv += __shfl_xor(sv, 32);
        if (lane == 0) wsum[(T_CNT - 1) & 1][wv] = sv;
    }
    __syncthreads();
    if (tid == 0) {
        for (int tm = T_CNT - 2; tm < T_CNT; ++tm) {
            const float* wp = wsum[tm & 1];
            float sg = (((wp[0] + wp[1]) + (wp[2] + wp[3])) +
                        ((wp[4] + wp[5]) + (wp[6] + wp[7]))) +
                       (((wp[8] + wp[9]) + (wp[10] + wp[11])) +
                        ((wp[12] + wp[13]) + (wp[14] + wp[15]))) + blin;
            const float sigma = fabsf(sg);
            sig_out[tm] = sigma;
            const float diff = zbuf[tm] - febuf[tm];
            ll -= (diff * diff) / (2.f * sigma * sigma);
        }
        atomicAdd(out, ll);
    }
}

extern "C" void kernel_launch(void* const* d_in, const int* in_sizes, int n_in,
                              void* d_out, int out_size, void* d_ws, size_t ws_size,
                              hipStream_t stream) {
    (void)in_sizes; (void)n_in; (void)out_size;
    const float* input_data = (const float*)d_in[0];
    const float* hidden     = (const float*)d_in[1];
    const float* fe         = (const float*)d_in[2];
    const float* W_ih       = (const float*)d_in[3];
    const float* W_hh       = (const float*)d_in[4];
    const float* b_ih       = (const float*)d_in[5];
    const float* b_hh       = (const float*)d_in[6];
    const float* W_lin      = (const float*)d_in[7];
    const float* b_lin      = (const float*)d_in[8];
    float* out = (float*)d_out;

    hipMemsetAsync(d_out, 0, sizeof(float), stream);

    const size_t u_bytes = (size_t)S_CNT * T_CNT * H_DIM * sizeof(float);
    const size_t p_bytes = (size_t)S_CNT * T_CNT * 16 * sizeof(float);

    if (ws_size >= u_bytes + p_bytes) {
        float* U = (float*)d_ws;
        float* P = (float*)((char*)d_ws + u_bytes);
        precompute_u_kernel<<<dim3(S_CNT, 16), 256, 0, stream>>>(
            input_data, W_ih, b_ih, b_hh, U);
        rnn_main2<<<dim3(S_CNT), dim3(NTHR), 0, stream>>>(
            hidden, W_hh, W_lin, U, P);
        finalize_kernel<<<dim3(S_CNT), 256, 0, stream>>>(
            input_data, fe, b_lin, P, out);
    } else {
        rnn_fallback_kernel<<<dim3(S_CNT), dim3(NTHR), 0, stream>>>(
            input_data, hidden, fe, W_ih, W_hh, b_ih, b_hh, W_lin, b_lin, out);
    }
}

// Round 5
// 1999.879 us; speedup vs baseline: 1.2074x; 1.2074x over previous
//
#include <hip/hip_runtime.h>
#include <cmath>

#define S_CNT 50
#define T_CNT 2048
#define I_DIM 64
#define H_DIM 256
#define NTHR  1024

typedef float vf2 __attribute__((ext_vector_type(2)));

__device__ __forceinline__ float fast_tanh(float x) {
    float e = __expf(2.0f * x);
    return 1.0f - __fdividef(2.0f, e + 1.0f);
}

__device__ __forceinline__ vf2 pkfma(vf2 a, vf2 b, vf2 c) {
#if __has_builtin(__builtin_elementwise_fma)
    return __builtin_elementwise_fma(a, b, c);
#else
    vf2 r; r.x = fmaf(a.x, b.x, c.x); r.y = fmaf(a.y, b.y, c.y); return r;
#endif
}

__device__ __forceinline__ float fma4(const float4 w, const float4 h, float a) {
    a = fmaf(w.x, h.x, a);
    a = fmaf(w.y, h.y, a);
    a = fmaf(w.z, h.z, a);
    a = fmaf(w.w, h.w, a);
    return a;
}

// U[s][t][j] = b_ih[s][j] + b_hh[s][j] + W_ih[s][j]·x[s][t]
__launch_bounds__(256, 4)
__global__ void precompute_u_kernel(const float* __restrict__ input_data,
                                    const float* __restrict__ W_ih,
                                    const float* __restrict__ b_ih,
                                    const float* __restrict__ b_hh,
                                    float* __restrict__ U)
{
    const int s  = blockIdx.x;
    const int tb = blockIdx.y;   // 64 t-slices of 32 steps
    const int j  = threadIdx.x;

    float4 w[16];
    const float4* wrow =
        reinterpret_cast<const float4*>(W_ih + ((size_t)s * H_DIM + j) * I_DIM);
#pragma unroll
    for (int k = 0; k < 16; ++k) w[k] = wrow[k];
    const float bsum = b_ih[s * H_DIM + j] + b_hh[s * H_DIM + j];

    __shared__ float xs[32][I_DIM];
    const float* inb = input_data + (size_t)s * T_CNT * 65;
    float* Ub = U + (size_t)s * T_CNT * H_DIM;

    const int t0 = tb * 32;
    for (int idx = j; idx < 32 * I_DIM; idx += 256) {
        const int row = idx >> 6, col = idx & 63;
        xs[row][col] = inb[(size_t)(t0 + row) * 65 + 1 + col];
    }
    __syncthreads();
    for (int tt = 0; tt < 32; ++tt) {
        const float4* xv = reinterpret_cast<const float4*>(&xs[tt][0]);
        float a0 = bsum, a1 = 0.f, a2 = 0.f, a3 = 0.f;
#pragma unroll
        for (int k = 0; k < 16; k += 4) {
            a0 = fma4(w[k],     xv[k],     a0);
            a1 = fma4(w[k + 1], xv[k + 1], a1);
            a2 = fma4(w[k + 2], xv[k + 2], a2);
            a3 = fma4(w[k + 3], xv[k + 3], a3);
        }
        Ub[(size_t)(t0 + tt) * H_DIM + j] = (a0 + a1) + (a2 + a3);
    }
}

// Main recurrence. tid = j*4 + q: thread owns row j, float4 col-chunks
// f = 4m+q. Packed-fp32 FMAs (v_pk_fma_f32). After computing h_t, the
// q==0 lanes overwrite U[s][t][j] (already consumed) with h_t; sigma and
// log-lik are computed by finalize_kernel off the critical path.
__launch_bounds__(NTHR, 4)
__global__ void rnn_main3(const float* __restrict__ hidden,
                          const float* __restrict__ W_hh,
                          float* __restrict__ U)
{
    const int s   = blockIdx.x;
    const int tid = threadIdx.x;
    const int j   = tid >> 2;
    const int q   = tid & 3;

    __shared__ float hA[H_DIM];
    __shared__ float hB[H_DIM];

    if (tid < H_DIM) hA[tid] = hidden[s * H_DIM + tid];

    // weights as 32 packed float2 (striped f = 4m+q)
    vf2 w2[32];
    {
        const float4* wrow =
            reinterpret_cast<const float4*>(W_hh + ((size_t)s * H_DIM + j) * H_DIM);
#pragma unroll
        for (int m = 0; m < 16; ++m) {
            const float4 wv = wrow[4 * m + q];
            w2[2 * m]     = vf2{wv.x, wv.y};
            w2[2 * m + 1] = vf2{wv.z, wv.w};
        }
    }

    float* Ub = U + (size_t)s * T_CNT * H_DIM;
    const float* uq = Ub + j;     // load pointer (t=0 first)
    float*       us = Ub + j;     // store pointer (t=0 first)
    float ucur = uq[0];
    uq += H_DIM;                  // now points at t=1

    __syncthreads();

#define RNN_STEP(HRD, HWR, TSTEP)                                            \
    {                                                                        \
        const float unext = uq[0];  /* prefetch t+1 (U padded at end) */     \
        uq += H_DIM;                                                         \
        const float4* hv = reinterpret_cast<const float4*>(HRD);             \
        vf2 a0 = vf2{0.f, 0.f}, a1 = vf2{0.f, 0.f};                          \
        vf2 a2 = vf2{0.f, 0.f}, a3 = vf2{0.f, 0.f};                          \
        _Pragma("unroll")                                                    \
        for (int m = 0; m < 16; m += 2) {                                    \
            const float4 h4a = hv[4 * m + q];                                \
            const float4 h4b = hv[4 * (m + 1) + q];                          \
            a0 = pkfma(w2[2 * m],     vf2{h4a.x, h4a.y}, a0);                \
            a1 = pkfma(w2[2 * m + 1], vf2{h4a.z, h4a.w}, a1);                \
            a2 = pkfma(w2[2 * m + 2], vf2{h4b.x, h4b.y}, a2);                \
            a3 = pkfma(w2[2 * m + 3], vf2{h4b.z, h4b.w}, a3);               \
        }                                                                    \
        const vf2 aa = (a0 + a1) + (a2 + a3);                                \
        float dot = aa.x + aa.y;                                             \
        dot += __shfl_xor(dot, 1);                                           \
        dot += __shfl_xor(dot, 2);                                           \
        const float hval = fast_tanh(dot + ucur);                            \
        if (q == 0) { (HWR)[j] = hval; us[0] = hval; }                       \
        us += H_DIM;                                                         \
        ucur = unext;                                                        \
    }

    for (int t = 0; t < T_CNT; t += 2) {
        RNN_STEP(hA, hB, t)
        __syncthreads();
        RNN_STEP(hB, hA, t + 1)
        __syncthreads();
    }
#undef RNN_STEP
}

// finalize: sigma[s][t] = |W_lin·h_t + b_lin|, log-lik reduction.
// H == U buffer (overwritten by rnn_main3 with h_t).
__launch_bounds__(256, 4)
__global__ void finalize_kernel(const float* __restrict__ input_data,
                                const float* __restrict__ fe,
                                const float* __restrict__ W_lin,
                                const float* __restrict__ b_lin,
                                const float* __restrict__ H,
                                float* __restrict__ out)
{
    const int s    = blockIdx.x;
    const int tb   = blockIdx.y;   // 4 slices of 512 timesteps
    const int tid  = threadIdx.x;
    const int wave = tid >> 6;
    const int lane = tid & 63;

    const float4 wl =
        reinterpret_cast<const float4*>(W_lin + s * H_DIM)[lane];
    const float blin = b_lin[s];
    const float* Hb  = H + (size_t)s * T_CNT * H_DIM;
    const float* inb = input_data + (size_t)s * T_CNT * 65;
    const float* feb = fe + (size_t)s * T_CNT;
    float* sig_out   = out + 1 + (size_t)s * T_CNT;

    float ll = 0.f;
    for (int i = 0; i < 128; ++i) {
        const int t = tb * 512 + 4 * i + wave;
        const float4 h4 =
            reinterpret_cast<const float4*>(Hb + (size_t)t * H_DIM)[lane];
        float d = fma4(wl, h4, 0.f);
#pragma unroll
        for (int m = 1; m <= 32; m <<= 1) d += __shfl_xor(d, m);
        const float sigma = fabsf(d + blin);
        if (lane == 0) {
            sig_out[t] = sigma;
            const float diff = inb[(size_t)t * 65] - feb[t];
            ll -= (diff * diff) / (2.f * sigma * sigma);
        }
    }
    __shared__ float red[4];
    if (lane == 0) red[wave] = ll;
    __syncthreads();
    if (tid == 0) atomicAdd(out, (red[0] + red[1]) + (red[2] + red[3]));
}

// ---------------- fallback (no workspace): round-3 style, self-contained ----
__launch_bounds__(NTHR, 4)
__global__ void rnn_fallback_kernel(const float* __restrict__ input_data,
                                    const float* __restrict__ hidden,
                                    const float* __restrict__ fe,
                                    const float* __restrict__ W_ih,
                                    const float* __restrict__ W_hh,
                                    const float* __restrict__ b_ih,
                                    const float* __restrict__ b_hh,
                                    const float* __restrict__ W_lin,
                                    const float* __restrict__ b_lin,
                                    float* __restrict__ out)
{
    const int s    = blockIdx.x;
    const int tid  = threadIdx.x;
    const int j    = tid >> 2;
    const int q    = tid & 3;
    const int lane = tid & 63;
    const int wv   = tid >> 6;

    __shared__ float hbuf[2][H_DIM];
    __shared__ float zbuf[T_CNT];
    __shared__ float febuf[T_CNT];
    __shared__ float wlin_lds[H_DIM];
    __shared__ float wsum[2][16];
    __shared__ float xbuf[64][I_DIM];

    const float* in_base = input_data + (size_t)s * T_CNT * 65;
    const float* fe_base = fe + (size_t)s * T_CNT;

    for (int t = tid; t < T_CNT; t += NTHR) {
        zbuf[t]  = in_base[(size_t)t * 65];
        febuf[t] = fe_base[t];
    }
    if (tid < H_DIM) {
        hbuf[1][tid]  = hidden[s * H_DIM + tid];
        wlin_lds[tid] = W_lin[s * H_DIM + tid];
    }

    float4 w[16];
    {
        const float4* wrow =
            reinterpret_cast<const float4*>(W_hh + ((size_t)s * H_DIM + j) * H_DIM);
#pragma unroll
        for (int m = 0; m < 16; ++m) w[m] = wrow[4 * m + q];
    }
    float4 wx[4];
    {
        const float4* wxrow =
            reinterpret_cast<const float4*>(W_ih + ((size_t)s * H_DIM + j) * I_DIM);
#pragma unroll
        for (int m = 0; m < 4; ++m) wx[m] = wxrow[4 * m + q];
    }
    const float badd = b_ih[s * H_DIM + j] + b_hh[s * H_DIM + j];
    const float blin = b_lin[s];
    float* sig_out = out + 1 + (size_t)s * T_CNT;

    float ll = 0.f, sv_prev = 0.f;
    __syncthreads();

    for (int c = 0; c < T_CNT / 64; ++c) {
        for (int idx = tid; idx < 64 * I_DIM; idx += NTHR) {
            const int row = idx >> 6, col = idx & 63;
            xbuf[row][col] = in_base[(size_t)(c * 64 + row) * 65 + 1 + col];
        }
        __syncthreads();
        for (int tt = 0; tt < 64; ++tt) {
            const int t  = c * 64 + tt;
            const int rp = (t + 1) & 1;
            {
                float sv = sv_prev;
                sv += __shfl_xor(sv, 4);
                sv += __shfl_xor(sv, 8);
                sv += __shfl_xor(sv, 16);
                sv += __shfl_xor(sv, 32);
                if (lane == 0) wsum[(t - 1) & 1][wv] = sv;
            }
            if (tid == 0 && t >= 2) {
                const int tm = t - 2;
                const float* wp = wsum[tm & 1];
                float sg = (((wp[0] + wp[1]) + (wp[2] + wp[3])) +
                            ((wp[4] + wp[5]) + (wp[6] + wp[7]))) +
                           (((wp[8] + wp[9]) + (wp[10] + wp[11])) +
                            ((wp[12] + wp[13]) + (wp[14] + wp[15]))) + blin;
                const float sigma = fabsf(sg);
                sig_out[tm] = sigma;
                const float diff = zbuf[tm] - febuf[tm];
                ll -= (diff * diff) / (2.f * sigma * sigma);
            }
            const float4* hv = reinterpret_cast<const float4*>(&hbuf[rp][0]);
            float a0 = 0.f, a1 = 0.f, a2 = 0.f, a3 = 0.f;
#pragma unroll
            for (int m = 0; m < 16; m += 4) {
                a0 = fma4(w[m],     hv[4 * (m + 0) + q], a0);
                a1 = fma4(w[m + 1], hv[4 * (m + 1) + q], a1);
                a2 = fma4(w[m + 2], hv[4 * (m + 2) + q], a2);
                a3 = fma4(w[m + 3], hv[4 * (m + 3) + q], a3);
            }
            const float4* xv = reinterpret_cast<const float4*>(&xbuf[tt][0]);
#pragma unroll
            for (int m = 0; m < 4; ++m) a0 = fma4(wx[m], xv[4 * m + q], a0);

            float dot = (a0 + a1) + (a2 + a3);
            dot += __shfl_xor(dot, 1);
            dot += __shfl_xor(dot, 2);
            const float h = fast_tanh(dot + badd);
            if (q == 0) hbuf[t & 1][j] = h;
            sv_prev = h * wlin_lds[j];
            __syncthreads();
        }
        __syncthreads();
    }
    {
        float sv = sv_prev;
        sv += __shfl_xor(sv, 4);
        sv += __shfl_xor(sv, 8);
        sv += __shfl_xor(sv, 16);
        sv += __shfl_xor(sv, 32);
        if (lane == 0) wsum[(T_CNT - 1) & 1][wv] = sv;
    }
    __syncthreads();
    if (tid == 0) {
        for (int tm = T_CNT - 2; tm < T_CNT; ++tm) {
            const float* wp = wsum[tm & 1];
            float sg = (((wp[0] + wp[1]) + (wp[2] + wp[3])) +
                        ((wp[4] + wp[5]) + (wp[6] + wp[7]))) +
                       (((wp[8] + wp[9]) + (wp[10] + wp[11])) +
                        ((wp[12] + wp[13]) + (wp[14] + wp[15]))) + blin;
            const float sigma = fabsf(sg);
            sig_out[tm] = sigma;
            const float diff = zbuf[tm] - febuf[tm];
            ll -= (diff * diff) / (2.f * sigma * sigma);
        }
        atomicAdd(out, ll);
    }
}

extern "C" void kernel_launch(void* const* d_in, const int* in_sizes, int n_in,
                              void* d_out, int out_size, void* d_ws, size_t ws_size,
                              hipStream_t stream) {
    (void)in_sizes; (void)n_in; (void)out_size;
    const float* input_data = (const float*)d_in[0];
    const float* hidden     = (const float*)d_in[1];
    const float* fe         = (const float*)d_in[2];
    const float* W_ih       = (const float*)d_in[3];
    const float* W_hh       = (const float*)d_in[4];
    const float* b_ih       = (const float*)d_in[5];
    const float* b_hh       = (const float*)d_in[6];
    const float* W_lin      = (const float*)d_in[7];
    const float* b_lin      = (const float*)d_in[8];
    float* out = (float*)d_out;

    hipMemsetAsync(d_out, 0, sizeof(float), stream);

    const size_t u_bytes   = (size_t)S_CNT * T_CNT * H_DIM * sizeof(float);
    const size_t pad_bytes = (size_t)H_DIM * sizeof(float);   // final prefetch overread

    if (ws_size >= u_bytes + pad_bytes) {
        float* U = (float*)d_ws;
        precompute_u_kernel<<<dim3(S_CNT, 64), 256, 0, stream>>>(
            input_data, W_ih, b_ih, b_hh, U);
        rnn_main3<<<dim3(S_CNT), dim3(NTHR), 0, stream>>>(hidden, W_hh, U);
        finalize_kernel<<<dim3(S_CNT, 4), 256, 0, stream>>>(
            input_data, fe, W_lin, b_lin, U, out);
    } else {
        rnn_fallback_kernel<<<dim3(S_CNT), dim3(NTHR), 0, stream>>>(
            input_data, hidden, fe, W_ih, W_hh, b_ih, b_hh, W_lin, b_lin, out);
    }
}

// Round 6
// 1700.890 us; speedup vs baseline: 1.4197x; 1.1758x over previous
//
#include <hip/hip_runtime.h>
#include <cmath>

#define S_CNT 50
#define T_CNT 2048
#define I_DIM 64
#define H_DIM 256

typedef float vf2 __attribute__((ext_vector_type(2)));

__device__ __forceinline__ float fast_tanh(float x) {
    float e = __expf(2.0f * x);
    return 1.0f - __fdividef(2.0f, e + 1.0f);
}

__device__ __forceinline__ vf2 pkfma(vf2 a, vf2 b, vf2 c) {
#if __has_builtin(__builtin_elementwise_fma)
    return __builtin_elementwise_fma(a, b, c);
#else
    vf2 r; r.x = fmaf(a.x, b.x, c.x); r.y = fmaf(a.y, b.y, c.y); return r;
#endif
}

__device__ __forceinline__ float fma4(const float4 w, const float4 h, float a) {
    a = fmaf(w.x, h.x, a);
    a = fmaf(w.y, h.y, a);
    a = fmaf(w.z, h.z, a);
    a = fmaf(w.w, h.w, a);
    return a;
}

// U[s][t][j] = b_ih[s][j] + b_hh[s][j] + W_ih[s][j]·x[s][t]
__launch_bounds__(256, 4)
__global__ void precompute_u_kernel(const float* __restrict__ input_data,
                                    const float* __restrict__ W_ih,
                                    const float* __restrict__ b_ih,
                                    const float* __restrict__ b_hh,
                                    float* __restrict__ U)
{
    const int s  = blockIdx.x;
    const int tb = blockIdx.y;   // 64 t-slices of 32 steps
    const int j  = threadIdx.x;

    float4 w[16];
    const float4* wrow =
        reinterpret_cast<const float4*>(W_ih + ((size_t)s * H_DIM + j) * I_DIM);
#pragma unroll
    for (int k = 0; k < 16; ++k) w[k] = wrow[k];
    const float bsum = b_ih[s * H_DIM + j] + b_hh[s * H_DIM + j];

    __shared__ float xs[32][I_DIM];
    const float* inb = input_data + (size_t)s * T_CNT * 65;
    float* Ub = U + (size_t)s * T_CNT * H_DIM;

    const int t0 = tb * 32;
    for (int idx = j; idx < 32 * I_DIM; idx += 256) {
        const int row = idx >> 6, col = idx & 63;
        xs[row][col] = inb[(size_t)(t0 + row) * 65 + 1 + col];
    }
    __syncthreads();
    for (int tt = 0; tt < 32; ++tt) {
        const float4* xv = reinterpret_cast<const float4*>(&xs[tt][0]);
        float a0 = bsum, a1 = 0.f, a2 = 0.f, a3 = 0.f;
#pragma unroll
        for (int k = 0; k < 16; k += 4) {
            a0 = fma4(w[k],     xv[k],     a0);
            a1 = fma4(w[k + 1], xv[k + 1], a1);
            a2 = fma4(w[k + 2], xv[k + 2], a2);
            a3 = fma4(w[k + 3], xv[k + 3], a3);
        }
        Ub[(size_t)(t0 + tt) * H_DIM + j] = (a0 + a1) + (a2 + a3);
    }
}

// Main recurrence, 512 threads: tid = g*8 + p. Group g owns rows 4g..4g+3;
// lane p owns float4 col-chunks f = 8m+p (m=0..7), i.e. 32 h-floats shared
// across the 4 rows. Per step per wave: 8 ds_read_b128 + 7 bpermute
// (reduce-scatter 4 vals over 8 lanes) + 1 ds_write_b32. h_t overwrites the
// consumed U slot (fp32) for the finalize kernel; sigma/log-lik off-path.
__launch_bounds__(512, 2)
__global__ void rnn_main4(const float* __restrict__ hidden,
                          const float* __restrict__ W_hh,
                          float* __restrict__ U)
{
    const int s    = blockIdx.x;
    const int tid  = threadIdx.x;
    const int g    = tid >> 3;    // 0..63: row group (rows 4g..4g+3)
    const int p    = tid & 7;     // col slice
    const int jown = 4 * g + (p >> 1);

    __shared__ __align__(16) float hA[H_DIM];
    __shared__ __align__(16) float hB[H_DIM];

    if (tid < H_DIM) hA[tid] = hidden[s * H_DIM + tid];

    // weights: 4 rows x 8 chunks of float4 (f = 8m+p), as packed vf2 pairs
    vf2 w2[4][16];
#pragma unroll
    for (int r = 0; r < 4; ++r) {
        const float4* wrow = reinterpret_cast<const float4*>(
            W_hh + ((size_t)s * H_DIM + 4 * g + r) * H_DIM);
#pragma unroll
        for (int m = 0; m < 8; ++m) {
            const float4 wv = wrow[8 * m + p];
            w2[r][2 * m]     = vf2{wv.x, wv.y};
            w2[r][2 * m + 1] = vf2{wv.z, wv.w};
        }
    }

    float* Ub = U + (size_t)s * T_CNT * H_DIM;
    const float* uq = Ub + jown;
    float*       us = Ub + jown;
    float ucur = *uq;
    uq += H_DIM;

    __syncthreads();

#define RNN_STEP(HRD, HWR)                                                    \
    {                                                                         \
        const float unext = *uq;   /* prefetch t+1 (U padded at end) */       \
        uq += H_DIM;                                                          \
        const float4* hv = reinterpret_cast<const float4*>(HRD);              \
        vf2 a0 = vf2{0.f, 0.f}, b0 = vf2{0.f, 0.f};                           \
        vf2 a1 = vf2{0.f, 0.f}, b1 = vf2{0.f, 0.f};                           \
        vf2 a2 = vf2{0.f, 0.f}, b2 = vf2{0.f, 0.f};                           \
        vf2 a3 = vf2{0.f, 0.f}, b3 = vf2{0.f, 0.f};                           \
        _Pragma("unroll")                                                     \
        for (int m = 0; m < 8; ++m) {                                         \
            const float4 h4 = hv[8 * m + p];                                  \
            const vf2 hlo = vf2{h4.x, h4.y};                                  \
            const vf2 hhi = vf2{h4.z, h4.w};                                  \
            a0 = pkfma(w2[0][2 * m], hlo, a0);                                \
            b0 = pkfma(w2[0][2 * m + 1], hhi, b0);                            \
            a1 = pkfma(w2[1][2 * m], hlo, a1);                                \
            b1 = pkfma(w2[1][2 * m + 1], hhi, b1);                            \
            a2 = pkfma(w2[2][2 * m], hlo, a2);                                \
            b2 = pkfma(w2[2][2 * m + 1], hhi, b2);                            \
            a3 = pkfma(w2[3][2 * m], hlo, a3);                                \
            b3 = pkfma(w2[3][2 * m + 1], hhi, b3);                            \
        }                                                                     \
        const vf2 s0v = a0 + b0, s1v = a1 + b1;                               \
        const vf2 s2v = a2 + b2, s3v = a3 + b3;                               \
        float d0 = s0v.x + s0v.y, d1 = s1v.x + s1v.y;                         \
        float d2 = s2v.x + s2v.y, d3 = s3v.x + s3v.y;                         \
        d0 += __shfl_xor(d0, 4);  d1 += __shfl_xor(d1, 4);                    \
        d2 += __shfl_xor(d2, 4);  d3 += __shfl_xor(d3, 4);                    \
        float e0 = (p & 4) ? d2 : d0;                                         \
        float e1 = (p & 4) ? d3 : d1;                                         \
        e0 += __shfl_xor(e0, 2);  e1 += __shfl_xor(e1, 2);                    \
        float fr = (p & 2) ? e1 : e0;                                         \
        fr += __shfl_xor(fr, 1);                                              \
        const float hval = fast_tanh(fr + ucur);                              \
        if (!(p & 1)) { (HWR)[jown] = hval; *us = hval; }                     \
        us += H_DIM;                                                          \
        ucur = unext;                                                         \
    }

    for (int t = 0; t < T_CNT; t += 2) {
        RNN_STEP(hA, hB)
        __syncthreads();
        RNN_STEP(hB, hA)
        __syncthreads();
    }
#undef RNN_STEP
}

// finalize: sigma[s][t] = |W_lin·h_t + b_lin|, log-lik reduction.
// H == U buffer (overwritten by rnn_main4 with h_t).
__launch_bounds__(256, 4)
__global__ void finalize_kernel(const float* __restrict__ input_data,
                                const float* __restrict__ fe,
                                const float* __restrict__ W_lin,
                                const float* __restrict__ b_lin,
                                const float* __restrict__ H,
                                float* __restrict__ out)
{
    const int s    = blockIdx.x;
    const int tb   = blockIdx.y;   // 4 slices of 512 timesteps
    const int tid  = threadIdx.x;
    const int wave = tid >> 6;
    const int lane = tid & 63;

    const float4 wl =
        reinterpret_cast<const float4*>(W_lin + s * H_DIM)[lane];
    const float blin = b_lin[s];
    const float* Hb  = H + (size_t)s * T_CNT * H_DIM;
    const float* inb = input_data + (size_t)s * T_CNT * 65;
    const float* feb = fe + (size_t)s * T_CNT;
    float* sig_out   = out + 1 + (size_t)s * T_CNT;

    float ll = 0.f;
    for (int i = 0; i < 128; ++i) {
        const int t = tb * 512 + 4 * i + wave;
        const float4 h4 =
            reinterpret_cast<const float4*>(Hb + (size_t)t * H_DIM)[lane];
        float d = fma4(wl, h4, 0.f);
#pragma unroll
        for (int m = 1; m <= 32; m <<= 1) d += __shfl_xor(d, m);
        const float sigma = fabsf(d + blin);
        if (lane == 0) {
            sig_out[t] = sigma;
            const float diff = inb[(size_t)t * 65] - feb[t];
            ll -= (diff * diff) / (2.f * sigma * sigma);
        }
    }
    __shared__ float red[4];
    if (lane == 0) red[wave] = ll;
    __syncthreads();
    if (tid == 0) atomicAdd(out, (red[0] + red[1]) + (red[2] + red[3]));
}

// ---------------- fallback (no workspace): round-3 style, self-contained ----
__launch_bounds__(1024, 4)
__global__ void rnn_fallback_kernel(const float* __restrict__ input_data,
                                    const float* __restrict__ hidden,
                                    const float* __restrict__ fe,
                                    const float* __restrict__ W_ih,
                                    const float* __restrict__ W_hh,
                                    const float* __restrict__ b_ih,
                                    const float* __restrict__ b_hh,
                                    const float* __restrict__ W_lin,
                                    const float* __restrict__ b_lin,
                                    float* __restrict__ out)
{
    const int s    = blockIdx.x;
    const int tid  = threadIdx.x;
    const int j    = tid >> 2;
    const int q    = tid & 3;
    const int lane = tid & 63;
    const int wv   = tid >> 6;

    __shared__ float hbuf[2][H_DIM];
    __shared__ float zbuf[T_CNT];
    __shared__ float febuf[T_CNT];
    __shared__ float wlin_lds[H_DIM];
    __shared__ float wsum[2][16];
    __shared__ float xbuf[64][I_DIM];

    const float* in_base = input_data + (size_t)s * T_CNT * 65;
    const float* fe_base = fe + (size_t)s * T_CNT;

    for (int t = tid; t < T_CNT; t += 1024) {
        zbuf[t]  = in_base[(size_t)t * 65];
        febuf[t] = fe_base[t];
    }
    if (tid < H_DIM) {
        hbuf[1][tid]  = hidden[s * H_DIM + tid];
        wlin_lds[tid] = W_lin[s * H_DIM + tid];
    }

    float4 w[16];
    {
        const float4* wrow =
            reinterpret_cast<const float4*>(W_hh + ((size_t)s * H_DIM + j) * H_DIM);
#pragma unroll
        for (int m = 0; m < 16; ++m) w[m] = wrow[4 * m + q];
    }
    float4 wx[4];
    {
        const float4* wxrow =
            reinterpret_cast<const float4*>(W_ih + ((size_t)s * H_DIM + j) * I_DIM);
#pragma unroll
        for (int m = 0; m < 4; ++m) wx[m] = wxrow[4 * m + q];
    }
    const float badd = b_ih[s * H_DIM + j] + b_hh[s * H_DIM + j];
    const float blin = b_lin[s];
    float* sig_out = out + 1 + (size_t)s * T_CNT;

    float ll = 0.f, sv_prev = 0.f;
    __syncthreads();

    for (int c = 0; c < T_CNT / 64; ++c) {
        for (int idx = tid; idx < 64 * I_DIM; idx += 1024) {
            const int row = idx >> 6, col = idx & 63;
            xbuf[row][col] = in_base[(size_t)(c * 64 + row) * 65 + 1 + col];
        }
        __syncthreads();
        for (int tt = 0; tt < 64; ++tt) {
            const int t  = c * 64 + tt;
            const int rp = (t + 1) & 1;
            {
                float sv = sv_prev;
                sv += __shfl_xor(sv, 4);
                sv += __shfl_xor(sv, 8);
                sv += __shfl_xor(sv, 16);
                sv += __shfl_xor(sv, 32);
                if (lane == 0) wsum[(t - 1) & 1][wv] = sv;
            }
            if (tid == 0 && t >= 2) {
                const int tm = t - 2;
                const float* wp = wsum[tm & 1];
                float sg = (((wp[0] + wp[1]) + (wp[2] + wp[3])) +
                            ((wp[4] + wp[5]) + (wp[6] + wp[7]))) +
                           (((wp[8] + wp[9]) + (wp[10] + wp[11])) +
                            ((wp[12] + wp[13]) + (wp[14] + wp[15]))) + blin;
                const float sigma = fabsf(sg);
                sig_out[tm] = sigma;
                const float diff = zbuf[tm] - febuf[tm];
                ll -= (diff * diff) / (2.f * sigma * sigma);
            }
            const float4* hv = reinterpret_cast<const float4*>(&hbuf[rp][0]);
            float a0 = 0.f, a1 = 0.f, a2 = 0.f, a3 = 0.f;
#pragma unroll
            for (int m = 0; m < 16; m += 4) {
                a0 = fma4(w[m],     hv[4 * (m + 0) + q], a0);
                a1 = fma4(w[m + 1], hv[4 * (m + 1) + q], a1);
                a2 = fma4(w[m + 2], hv[4 * (m + 2) + q], a2);
                a3 = fma4(w[m + 3], hv[4 * (m + 3) + q], a3);
            }
            const float4* xv = reinterpret_cast<const float4*>(&xbuf[tt][0]);
#pragma unroll
            for (int m = 0; m < 4; ++m) a0 = fma4(wx[m], xv[4 * m + q], a0);

            float dot = (a0 + a1) + (a2 + a3);
            dot += __shfl_xor(dot, 1);
            dot += __shfl_xor(dot, 2);
            const float h = fast_tanh(dot + badd);
            if (q == 0) hbuf[t & 1][j] = h;
            sv_prev = h * wlin_lds[j];
            __syncthreads();
        }
        __syncthreads();
    }
    {
        float sv = sv_prev;
        sv += __shfl_xor(sv, 4);
        sv += __shfl_xor(sv, 8);
        sv += __shfl_xor(sv, 16);
        sv += __shfl_xor(sv, 32);
        if (lane == 0) wsum[(T_CNT - 1) & 1][wv] = sv;
    }
    __syncthreads();
    if (tid == 0) {
        for (int tm = T_CNT - 2; tm < T_CNT; ++tm) {
            const float* wp = wsum[tm & 1];
            float sg = (((wp[0] + wp[1]) + (wp[2] + wp[3])) +
                        ((wp[4] + wp[5]) + (wp[6] + wp[7]))) +
                       (((wp[8] + wp[9]) + (wp[10] + wp[11])) +
                        ((wp[12] + wp[13]) + (wp[14] + wp[15]))) + blin;
            const float sigma = fabsf(sg);
            sig_out[tm] = sigma;
            const float diff = zbuf[tm] - febuf[tm];
            ll -= (diff * diff) / (2.f * sigma * sigma);
        }
        atomicAdd(out, ll);
    }
}

extern "C" void kernel_launch(void* const* d_in, const int* in_sizes, int n_in,
                              void* d_out, int out_size, void* d_ws, size_t ws_size,
                              hipStream_t stream) {
    (void)in_sizes; (void)n_in; (void)out_size;
    const float* input_data = (const float*)d_in[0];
    const float* hidden     = (const float*)d_in[1];
    const float* fe         = (const float*)d_in[2];
    const float* W_ih       = (const float*)d_in[3];
    const float* W_hh       = (const float*)d_in[4];
    const float* b_ih       = (const float*)d_in[5];
    const float* b_hh       = (const float*)d_in[6];
    const float* W_lin      = (const float*)d_in[7];
    const float* b_lin      = (const float*)d_in[8];
    float* out = (float*)d_out;

    hipMemsetAsync(d_out, 0, sizeof(float), stream);

    const size_t u_bytes   = (size_t)S_CNT * T_CNT * H_DIM * sizeof(float);
    const size_t pad_bytes = (size_t)H_DIM * sizeof(float);   // final prefetch overread

    if (ws_size >= u_bytes + pad_bytes) {
        float* U = (float*)d_ws;
        precompute_u_kernel<<<dim3(S_CNT, 64), 256, 0, stream>>>(
            input_data, W_ih, b_ih, b_hh, U);
        rnn_main4<<<dim3(S_CNT), dim3(512), 0, stream>>>(hidden, W_hh, U);
        finalize_kernel<<<dim3(S_CNT, 4), 256, 0, stream>>>(
            input_data, fe, W_lin, b_lin, U, out);
    } else {
        rnn_fallback_kernel<<<dim3(S_CNT), dim3(1024), 0, stream>>>(
            input_data, hidden, fe, W_ih, W_hh, b_ih, b_hh, W_lin, b_lin, out);
    }
}

// Round 7
// 1583.525 us; speedup vs baseline: 1.5249x; 1.0741x over previous
//
#include <hip/hip_runtime.h>
#include <cmath>

#define S_CNT 50
#define T_CNT 2048
#define I_DIM 64
#define H_DIM 256

typedef float vf2 __attribute__((ext_vector_type(2)));

__device__ __forceinline__ float fast_tanh(float x) {
    float e = __expf(2.0f * x);
    return 1.0f - __fdividef(2.0f, e + 1.0f);
}

__device__ __forceinline__ vf2 pkfma(vf2 a, vf2 b, vf2 c) {
#if __has_builtin(__builtin_elementwise_fma)
    return __builtin_elementwise_fma(a, b, c);
#else
    vf2 r; r.x = fmaf(a.x, b.x, c.x); r.y = fmaf(a.y, b.y, c.y); return r;
#endif
}

__device__ __forceinline__ float fma4(const float4 w, const float4 h, float a) {
    a = fmaf(w.x, h.x, a);
    a = fmaf(w.y, h.y, a);
    a = fmaf(w.z, h.z, a);
    a = fmaf(w.w, h.w, a);
    return a;
}

// x + quad_perm-DPP(x): VALU-pipe cross-lane add (no LDS traffic).
// CTRL: 0xB1 = xor1 ([1,0,3,2]), 0x4E = xor2 ([2,3,0,1]).
template <int CTRL>
__device__ __forceinline__ float dpp_xadd(float x) {
    const int xi = __float_as_int(x);
    const int yi = __builtin_amdgcn_update_dpp(xi, xi, CTRL, 0xF, 0xF, false);
    return x + __int_as_float(yi);
}

// x + swizzle_xor4(x): one DS op (BitMode: xor_mask=4 -> 0x101F).
__device__ __forceinline__ float swz_xadd4(float x) {
    const int yi = __builtin_amdgcn_ds_swizzle(__float_as_int(x), 0x101F);
    return x + __int_as_float(yi);
}

// U[s][t][j] = b_ih[s][j] + b_hh[s][j] + W_ih[s][j]·x[s][t]
__launch_bounds__(256, 4)
__global__ void precompute_u_kernel(const float* __restrict__ input_data,
                                    const float* __restrict__ W_ih,
                                    const float* __restrict__ b_ih,
                                    const float* __restrict__ b_hh,
                                    float* __restrict__ U)
{
    const int s  = blockIdx.x;
    const int tb = blockIdx.y;   // 16 t-slices of 128 steps
    const int j  = threadIdx.x;

    float4 w[16];
    const float4* wrow =
        reinterpret_cast<const float4*>(W_ih + ((size_t)s * H_DIM + j) * I_DIM);
#pragma unroll
    for (int k = 0; k < 16; ++k) w[k] = wrow[k];
    const float bsum = b_ih[s * H_DIM + j] + b_hh[s * H_DIM + j];

    __shared__ float xs[32][I_DIM];
    const float* inb = input_data + (size_t)s * T_CNT * 65;
    float* Ub = U + (size_t)s * T_CNT * H_DIM;

    for (int c = 0; c < 4; ++c) {
        const int t0 = tb * 128 + c * 32;
        __syncthreads();
        for (int idx = j; idx < 32 * I_DIM; idx += 256) {
            const int row = idx >> 6, col = idx & 63;
            xs[row][col] = inb[(size_t)(t0 + row) * 65 + 1 + col];
        }
        __syncthreads();
        for (int tt = 0; tt < 32; ++tt) {
            const float4* xv = reinterpret_cast<const float4*>(&xs[tt][0]);
            float a0 = bsum, a1 = 0.f, a2 = 0.f, a3 = 0.f;
#pragma unroll
            for (int k = 0; k < 16; k += 4) {
                a0 = fma4(w[k],     xv[k],     a0);
                a1 = fma4(w[k + 1], xv[k + 1], a1);
                a2 = fma4(w[k + 2], xv[k + 2], a2);
                a3 = fma4(w[k + 3], xv[k + 3], a3);
            }
            Ub[(size_t)(t0 + tt) * H_DIM + j] = (a0 + a1) + (a2 + a3);
        }
    }
}

// Main recurrence, 512 threads: tid = g*8 + p. Group g owns rows 4g..4g+3;
// lane p owns float4 col-chunks f = 8m+p (m=0..7). Reduce-scatter of the 4
// row-partials over 8 lanes: xor1 (DPP) -> select -> xor2 (DPP) -> select ->
// xor4 (1 ds_swizzle). Lane p ends up owning row jown = 4g + (p&3); lanes
// p and p+4 are duplicates, p<4 writes. Per step per wave: 8 ds_read_b128 +
// 1 ds_swizzle + 1 ds_write_b32. h_t overwrites the consumed U slot.
__launch_bounds__(512, 2)
__global__ void rnn_main5(const float* __restrict__ hidden,
                          const float* __restrict__ W_hh,
                          float* __restrict__ U)
{
    const int s    = blockIdx.x;
    const int tid  = threadIdx.x;
    const int g    = tid >> 3;    // 0..63: row group (rows 4g..4g+3)
    const int p    = tid & 7;     // col slice
    const int jown = 4 * g + (p & 3);

    __shared__ __align__(16) float hA[H_DIM];
    __shared__ __align__(16) float hB[H_DIM];

    if (tid < H_DIM) hA[tid] = hidden[s * H_DIM + tid];

    // weights: 4 rows x 8 chunks of float4 (f = 8m+p), as packed vf2 pairs
    vf2 w2[4][16];
#pragma unroll
    for (int r = 0; r < 4; ++r) {
        const float4* wrow = reinterpret_cast<const float4*>(
            W_hh + ((size_t)s * H_DIM + 4 * g + r) * H_DIM);
#pragma unroll
        for (int m = 0; m < 8; ++m) {
            const float4 wv = wrow[8 * m + p];
            w2[r][2 * m]     = vf2{wv.x, wv.y};
            w2[r][2 * m + 1] = vf2{wv.z, wv.w};
        }
    }

    float* Ub = U + (size_t)s * T_CNT * H_DIM;
    const float* uq = Ub + jown;
    float*       us = Ub + jown;
    float ucur = *uq;
    uq += H_DIM;

    const bool wsel  = (p < 4);
    const bool sel1  = (p & 1);
    const bool sel2  = (p & 2);

    __syncthreads();

#define RNN_STEP(HRD, HWR)                                                    \
    {                                                                         \
        const float unext = *uq;   /* prefetch t+1 (U padded at end) */       \
        uq += H_DIM;                                                          \
        const float4* hv = reinterpret_cast<const float4*>(HRD);              \
        vf2 a0 = vf2{0.f, 0.f}, b0 = vf2{0.f, 0.f};                           \
        vf2 a1 = vf2{0.f, 0.f}, b1 = vf2{0.f, 0.f};                           \
        vf2 a2 = vf2{0.f, 0.f}, b2 = vf2{0.f, 0.f};                           \
        vf2 a3 = vf2{0.f, 0.f}, b3 = vf2{0.f, 0.f};                           \
        _Pragma("unroll")                                                     \
        for (int m = 0; m < 8; ++m) {                                         \
            const float4 h4 = hv[8 * m + p];                                  \
            const vf2 hlo = vf2{h4.x, h4.y};                                  \
            const vf2 hhi = vf2{h4.z, h4.w};                                  \
            a0 = pkfma(w2[0][2 * m], hlo, a0);                                \
            b0 = pkfma(w2[0][2 * m + 1], hhi, b0);                            \
            a1 = pkfma(w2[1][2 * m], hlo, a1);                                \
            b1 = pkfma(w2[1][2 * m + 1], hhi, b1);                            \
            a2 = pkfma(w2[2][2 * m], hlo, a2);                                \
            b2 = pkfma(w2[2][2 * m + 1], hhi, b2);                            \
            a3 = pkfma(w2[3][2 * m], hlo, a3);                                \
            b3 = pkfma(w2[3][2 * m + 1], hhi, b3);                            \
        }                                                                     \
        const vf2 s0v = a0 + b0, s1v = a1 + b1;                               \
        const vf2 s2v = a2 + b2, s3v = a3 + b3;                               \
        const float d0 = s0v.x + s0v.y, d1 = s1v.x + s1v.y;                   \
        const float d2 = s2v.x + s2v.y, d3 = s3v.x + s3v.y;                   \
        /* xor1 via DPP, keep 2 of 4 */                                       \
        const float e0 = dpp_xadd<0xB1>(d0);                                  \
        const float e1 = dpp_xadd<0xB1>(d1);                                  \
        const float e2 = dpp_xadd<0xB1>(d2);                                  \
        const float e3 = dpp_xadd<0xB1>(d3);                                  \
        const float c0 = sel1 ? e1 : e0;                                      \
        const float c1 = sel1 ? e3 : e2;                                      \
        /* xor2 via DPP, keep 1 of 2 */                                       \
        const float f0 = dpp_xadd<0x4E>(c0);                                  \
        const float f1 = dpp_xadd<0x4E>(c1);                                  \
        const float gg = sel2 ? f1 : f0;                                      \
        /* xor4 via one ds_swizzle */                                         \
        const float fr = swz_xadd4(gg);                                       \
        const float hval = fast_tanh(fr + ucur);                              \
        if (wsel) { (HWR)[jown] = hval; *us = hval; }                         \
        us += H_DIM;                                                          \
        ucur = unext;                                                         \
    }

    for (int t = 0; t < T_CNT; t += 2) {
        RNN_STEP(hA, hB)
        __syncthreads();
        RNN_STEP(hB, hA)
        __syncthreads();
    }
#undef RNN_STEP
}

// finalize: sigma[s][t] = |W_lin·h_t + b_lin|, log-lik reduction.
// H == U buffer (overwritten by rnn_main5 with h_t).
__launch_bounds__(256, 4)
__global__ void finalize_kernel(const float* __restrict__ input_data,
                                const float* __restrict__ fe,
                                const float* __restrict__ W_lin,
                                const float* __restrict__ b_lin,
                                const float* __restrict__ H,
                                float* __restrict__ out)
{
    const int s    = blockIdx.x;
    const int tb   = blockIdx.y;   // 4 slices of 512 timesteps
    const int tid  = threadIdx.x;
    const int wave = tid >> 6;
    const int lane = tid & 63;

    const float4 wl =
        reinterpret_cast<const float4*>(W_lin + s * H_DIM)[lane];
    const float blin = b_lin[s];
    const float* Hb  = H + (size_t)s * T_CNT * H_DIM;
    const float* inb = input_data + (size_t)s * T_CNT * 65;
    const float* feb = fe + (size_t)s * T_CNT;
    float* sig_out   = out + 1 + (size_t)s * T_CNT;

    float ll = 0.f;
    for (int i = 0; i < 128; ++i) {
        const int t = tb * 512 + 4 * i + wave;
        const float4 h4 =
            reinterpret_cast<const float4*>(Hb + (size_t)t * H_DIM)[lane];
        float d = fma4(wl, h4, 0.f);
#pragma unroll
        for (int m = 1; m <= 32; m <<= 1) d += __shfl_xor(d, m);
        const float sigma = fabsf(d + blin);
        if (lane == 0) {
            sig_out[t] = sigma;
            const float diff = inb[(size_t)t * 65] - feb[t];
            ll -= (diff * diff) / (2.f * sigma * sigma);
        }
    }
    __shared__ float red[4];
    if (lane == 0) red[wave] = ll;
    __syncthreads();
    if (tid == 0) atomicAdd(out, (red[0] + red[1]) + (red[2] + red[3]));
}

// ---------------- fallback (no workspace): round-3 style, self-contained ----
__launch_bounds__(1024, 4)
__global__ void rnn_fallback_kernel(const float* __restrict__ input_data,
                                    const float* __restrict__ hidden,
                                    const float* __restrict__ fe,
                                    const float* __restrict__ W_ih,
                                    const float* __restrict__ W_hh,
                                    const float* __restrict__ b_ih,
                                    const float* __restrict__ b_hh,
                                    const float* __restrict__ W_lin,
                                    const float* __restrict__ b_lin,
                                    float* __restrict__ out)
{
    const int s    = blockIdx.x;
    const int tid  = threadIdx.x;
    const int j    = tid >> 2;
    const int q    = tid & 3;
    const int lane = tid & 63;
    const int wv   = tid >> 6;

    __shared__ float hbuf[2][H_DIM];
    __shared__ float zbuf[T_CNT];
    __shared__ float febuf[T_CNT];
    __shared__ float wlin_lds[H_DIM];
    __shared__ float wsum[2][16];
    __shared__ float xbuf[64][I_DIM];

    const float* in_base = input_data + (size_t)s * T_CNT * 65;
    const float* fe_base = fe + (size_t)s * T_CNT;

    for (int t = tid; t < T_CNT; t += 1024) {
        zbuf[t]  = in_base[(size_t)t * 65];
        febuf[t] = fe_base[t];
    }
    if (tid < H_DIM) {
        hbuf[1][tid]  = hidden[s * H_DIM + tid];
        wlin_lds[tid] = W_lin[s * H_DIM + tid];
    }

    float4 w[16];
    {
        const float4* wrow =
            reinterpret_cast<const float4*>(W_hh + ((size_t)s * H_DIM + j) * H_DIM);
#pragma unroll
        for (int m = 0; m < 16; ++m) w[m] = wrow[4 * m + q];
    }
    float4 wx[4];
    {
        const float4* wxrow =
            reinterpret_cast<const float4*>(W_ih + ((size_t)s * H_DIM + j) * I_DIM);
#pragma unroll
        for (int m = 0; m < 4; ++m) wx[m] = wxrow[4 * m + q];
    }
    const float badd = b_ih[s * H_DIM + j] + b_hh[s * H_DIM + j];
    const float blin = b_lin[s];
    float* sig_out = out + 1 + (size_t)s * T_CNT;

    float ll = 0.f, sv_prev = 0.f;
    __syncthreads();

    for (int c = 0; c < T_CNT / 64; ++c) {
        for (int idx = tid; idx < 64 * I_DIM; idx += 1024) {
            const int row = idx >> 6, col = idx & 63;
            xbuf[row][col] = in_base[(size_t)(c * 64 + row) * 65 + 1 + col];
        }
        __syncthreads();
        for (int tt = 0; tt < 64; ++tt) {
            const int t  = c * 64 + tt;
            const int rp = (t + 1) & 1;
            {
                float sv = sv_prev;
                sv += __shfl_xor(sv, 4);
                sv += __shfl_xor(sv, 8);
                sv += __shfl_xor(sv, 16);
                sv += __shfl_xor(sv, 32);
                if (lane == 0) wsum[(t - 1) & 1][wv] = sv;
            }
            if (tid == 0 && t >= 2) {
                const int tm = t - 2;
                const float* wp = wsum[tm & 1];
                float sg = (((wp[0] + wp[1]) + (wp[2] + wp[3])) +
                            ((wp[4] + wp[5]) + (wp[6] + wp[7]))) +
                           (((wp[8] + wp[9]) + (wp[10] + wp[11])) +
                            ((wp[12] + wp[13]) + (wp[14] + wp[15]))) + blin;
                const float sigma = fabsf(sg);
                sig_out[tm] = sigma;
                const float diff = zbuf[tm] - febuf[tm];
                ll -= (diff * diff) / (2.f * sigma * sigma);
            }
            const float4* hv = reinterpret_cast<const float4*>(&hbuf[rp][0]);
            float a0 = 0.f, a1 = 0.f, a2 = 0.f, a3 = 0.f;
#pragma unroll
            for (int m = 0; m < 16; m += 4) {
                a0 = fma4(w[m],     hv[4 * (m + 0) + q], a0);
                a1 = fma4(w[m + 1], hv[4 * (m + 1) + q], a1);
                a2 = fma4(w[m + 2], hv[4 * (m + 2) + q], a2);
                a3 = fma4(w[m + 3], hv[4 * (m + 3) + q], a3);
            }
            const float4* xv = reinterpret_cast<const float4*>(&xbuf[tt][0]);
#pragma unroll
            for (int m = 0; m < 4; ++m) a0 = fma4(wx[m], xv[4 * m + q], a0);

            float dot = (a0 + a1) + (a2 + a3);
            dot += __shfl_xor(dot, 1);
            dot += __shfl_xor(dot, 2);
            const float h = fast_tanh(dot + badd);
            if (q == 0) hbuf[t & 1][j] = h;
            sv_prev = h * wlin_lds[j];
            __syncthreads();
        }
        __syncthreads();
    }
    {
        float sv = sv_prev;
        sv += __shfl_xor(sv, 4);
        sv += __shfl_xor(sv, 8);
        sv += __shfl_xor(sv, 16);
        sv += __shfl_xor(sv, 32);
        if (lane == 0) wsum[(T_CNT - 1) & 1][wv] = sv;
    }
    __syncthreads();
    if (tid == 0) {
        for (int tm = T_CNT - 2; tm < T_CNT; ++tm) {
            const float* wp = wsum[tm & 1];
            float sg = (((wp[0] + wp[1]) + (wp[2] + wp[3])) +
                        ((wp[4] + wp[5]) + (wp[6] + wp[7]))) +
                       (((wp[8] + wp[9]) + (wp[10] + wp[11])) +
                        ((wp[12] + wp[13]) + (wp[14] + wp[15]))) + blin;
            const float sigma = fabsf(sg);
            sig_out[tm] = sigma;
            const float diff = zbuf[tm] - febuf[tm];
            ll -= (diff * diff) / (2.f * sigma * sigma);
        }
        atomicAdd(out, ll);
    }
}

extern "C" void kernel_launch(void* const* d_in, const int* in_sizes, int n_in,
                              void* d_out, int out_size, void* d_ws, size_t ws_size,
                              hipStream_t stream) {
    (void)in_sizes; (void)n_in; (void)out_size;
    const float* input_data = (const float*)d_in[0];
    const float* hidden     = (const float*)d_in[1];
    const float* fe         = (const float*)d_in[2];
    const float* W_ih       = (const float*)d_in[3];
    const float* W_hh       = (const float*)d_in[4];
    const float* b_ih       = (const float*)d_in[5];
    const float* b_hh       = (const float*)d_in[6];
    const float* W_lin      = (const float*)d_in[7];
    const float* b_lin      = (const float*)d_in[8];
    float* out = (float*)d_out;

    hipMemsetAsync(d_out, 0, sizeof(float), stream);

    const size_t u_bytes   = (size_t)S_CNT * T_CNT * H_DIM * sizeof(float);
    const size_t pad_bytes = (size_t)H_DIM * sizeof(float);   // final prefetch overread

    if (ws_size >= u_bytes + pad_bytes) {
        float* U = (float*)d_ws;
        precompute_u_kernel<<<dim3(S_CNT, 16), 256, 0, stream>>>(
            input_data, W_ih, b_ih, b_hh, U);
        rnn_main5<<<dim3(S_CNT), dim3(512), 0, stream>>>(hidden, W_hh, U);
        finalize_kernel<<<dim3(S_CNT, 4), 256, 0, stream>>>(
            input_data, fe, W_lin, b_lin, U, out);
    } else {
        rnn_fallback_kernel<<<dim3(S_CNT), dim3(1024), 0, stream>>>(
            input_data, hidden, fe, W_ih, W_hh, b_ih, b_hh, W_lin, b_lin, out);
    }
}